// Round 1
// baseline (1025.574 us; speedup 1.0000x reference)
//
#include <hip/hip_runtime.h>
#include <math.h>

#define N_NODES 50000
#define N_EDGES 600000
#define NTILES (N_EDGES / 64)
#define NODE_TILES ((N_NODES + 31) / 32)

typedef __attribute__((ext_vector_type(8))) short bf16x8;
typedef __attribute__((ext_vector_type(4))) float f32x4;

__device__ __forceinline__ unsigned short f2bf(float f){
  union { float f; unsigned int u; } v; v.f = f;
  unsigned int u = v.u;
  unsigned int r = (u + 0x7fffu + ((u >> 16) & 1u)) >> 16;
  return (unsigned short)r;
}
__device__ __forceinline__ float gelu_f(float x){
  return 0.5f * x * (1.0f + erff(x * 0.70710678118654752440f));
}

// ---------------- weight packing: W[K][N] fp32 -> bf16 fragments ----------------
// out[((kt*N + n)*4 + q)*8 + j] = bf16(W[(kt*32 + q*8 + j)*N + n])
__global__ void pack_kernel(const float* __restrict__ W, unsigned short* __restrict__ out,
                            int K, int N){
  int id = blockIdx.x * 256 + threadIdx.x;
  if (id >= K * N) return;
  int j = id & 7;
  int q = (id >> 3) & 3;
  int rest = id >> 5;
  int n = rest % N;
  int kt = rest / N;
  int k = kt * 32 + q * 8 + j;
  out[id] = f2bf(W[(size_t)k * N + n]);
}

// ---------------- LN1: h = LN(x)*g+b, stored bf16 ----------------
__global__ __launch_bounds__(256) void ln1_kernel(const float* __restrict__ x,
                                                  const float* __restrict__ g,
                                                  const float* __restrict__ b,
                                                  unsigned short* __restrict__ h_bf, int n){
  int row = blockIdx.x * 4 + (threadIdx.x >> 6);
  if (row >= n) return;
  int lane = threadIdx.x & 63;
  const float* xr = x + (size_t)row * 128;
  float2 v = *(const float2*)(xr + lane * 2);
  float s = v.x + v.y;
  float s2 = v.x * v.x + v.y * v.y;
#pragma unroll
  for (int off = 32; off; off >>= 1){ s += __shfl_xor(s, off); s2 += __shfl_xor(s2, off); }
  float mu = s * (1.f / 128.f);
  float var = s2 * (1.f / 128.f) - mu * mu;
  float rs = rsqrtf(var + 1e-5f);
  int c = lane * 2;
  ushort2 o;
  o.x = f2bf((v.x - mu) * rs * g[c] + b[c]);
  o.y = f2bf((v.y - mu) * rs * g[c + 1] + b[c + 1]);
  *(ushort2*)(h_bf + (size_t)row * 128 + c) = o;
}

// ---------------- persistent column-split edge kernel ----------------
// v2: 3 barriers/tile (was 4), register-prefetched gathers (T14), merged
// gate+msg1 phase sharing A-fragments, wave-private gate table (no barrier),
// transposed msg1 epilogue (ds_write_b64). msg2 kept untransposed so the
// agg atomics stay 64B-line-contiguous per 16 lanes (memory-side merge).
__global__ __launch_bounds__(256, 2) void edge_kernel(
    const unsigned short* __restrict__ h_bf,
    const int* __restrict__ esrc, const int* __restrict__ edst,
    const float* __restrict__ emb,
    const unsigned short* __restrict__ Wm1p, const float* __restrict__ bm1,
    const unsigned short* __restrict__ Wm2p, const float* __restrict__ bm2,
    const unsigned short* __restrict__ Wg1p, const float* __restrict__ bg1,
    const float* __restrict__ wg2, const float* __restrict__ bg2,
    float* __restrict__ out_e, float* __restrict__ agg, float* __restrict__ deg)
{
  // A = [hd(0:128) | hs(128:256) | emb(256:320)], bf16, stride 328 (2-way banks, free)
  __shared__ __align__(16) unsigned short smA[64][328];
  __shared__ __align__(16) unsigned short smT[64][136];
  __shared__ __align__(16) float smGP[4][64];
  __shared__ __align__(16) float smGateW[4][64];   // per-wave private copy
  __shared__ int smDst[64];

  const int t = threadIdx.x;
  const int wave = t >> 6, lane = t & 63;
  const int q = lane >> 4, ln = lane & 15;
  const int kq = q * 8;

  // ---- per-wave weight slices in registers (loaded once) ----
  bf16x8 wg[10][2], w1[6][2], w2[4][2];
  float bg1r[2], wg2r[2], bm2r[2];
  float4 bm1t[2];
#pragma unroll
  for (int j = 0; j < 2; j++){
    const int col = wave * 32 + j * 16 + ln;
    bg1r[j] = bg1[col]; wg2r[j] = wg2[col]; bm2r[j] = bm2[col];
    bm1t[j] = *(const float4*)(bm1 + wave * 32 + j * 16 + q * 4);  // transposed-epilogue bias
#pragma unroll
    for (int kt = 0; kt < 10; kt++) wg[kt][j] = *(const bf16x8*)(Wg1p + (((size_t)kt * 128 + col) * 4 + q) * 8);
#pragma unroll
    for (int kt = 0; kt < 6; kt++)  w1[kt][j] = *(const bf16x8*)(Wm1p + (((size_t)kt * 128 + col) * 4 + q) * 8);
#pragma unroll
    for (int kt = 0; kt < 4; kt++)  w2[kt][j] = *(const bf16x8*)(Wm2p + (((size_t)kt * 128 + col) * 4 + q) * 8);
  }
  const float bg2v = bg2[0];
  const int r4 = t >> 2, i4 = t & 3;   // staging: 4 threads per edge row

  // ---- prefetch tile 0 gathers into registers ----
  uint4 hdR[4], hsR[4];
  float4 emR[4];
  int dstR;
  {
    const int e = blockIdx.x * 64 + r4;
    dstR = edst[e];
    const int ss = esrc[e];
    const uint4* hdp = (const uint4*)(h_bf + (size_t)dstR * 128 + i4 * 32);
    const uint4* hsp = (const uint4*)(h_bf + (size_t)ss * 128 + i4 * 32);
#pragma unroll
    for (int k2 = 0; k2 < 4; k2++){ hdR[k2] = hdp[k2]; hsR[k2] = hsp[k2]; }
    const float4* ep = (const float4*)(emb + (size_t)e * 64 + i4 * 16);
#pragma unroll
    for (int k2 = 0; k2 < 4; k2++) emR[k2] = ep[k2];
  }

  for (int tile = blockIdx.x; tile < NTILES; tile += gridDim.x){
    const int e0 = tile * 64;
    __syncthreads();   // syncA: prior tile's smA/smT/smDst consumers done

    // ---- stage A + dst from prefetched registers (pure LDS writes) ----
    {
      if (i4 == 0){ smDst[r4] = dstR; atomicAdd(&deg[dstR], 1.0f); }
      uint4* a0 = (uint4*)&smA[r4][i4 * 32];
      uint4* a1 = (uint4*)&smA[r4][128 + i4 * 32];
#pragma unroll
      for (int k2 = 0; k2 < 4; k2++){ a0[k2] = hdR[k2]; a1[k2] = hsR[k2]; }
#pragma unroll
      for (int k2 = 0; k2 < 4; k2++){
        float4 f = emR[k2];
        ushort4 u; u.x = f2bf(f.x); u.y = f2bf(f.y); u.z = f2bf(f.z); u.w = f2bf(f.w);
        *(ushort4*)&smA[r4][256 + i4 * 16 + k2 * 4] = u;
      }
    }
    __syncthreads();   // syncB: smA ready

    // ---- issue next tile's gathers (hidden under the MFMA phase below) ----
    {
      const int tn = tile + gridDim.x;
      const int eb = (tn < NTILES) ? tn * 64 : e0;   // clamp: harmless reload
      const int e = eb + r4;
      dstR = edst[e];
      const int ss = esrc[e];
      const uint4* hdp = (const uint4*)(h_bf + (size_t)dstR * 128 + i4 * 32);
      const uint4* hsp = (const uint4*)(h_bf + (size_t)ss * 128 + i4 * 32);
#pragma unroll
      for (int k2 = 0; k2 < 4; k2++){ hdR[k2] = hdp[k2]; hsR[k2] = hsp[k2]; }
      const float4* ep = (const float4*)(emb + (size_t)e * 64 + i4 * 16);
#pragma unroll
      for (int k2 = 0; k2 < 4; k2++) emR[k2] = ep[k2];
    }

    // ---- merged gate + msg1 phase (both read smA; hs/emb A-frags shared) ----
    {
      f32x4 accg[4][2], accm[4][2];
#pragma unroll
      for (int rt = 0; rt < 4; rt++)
#pragma unroll
        for (int j = 0; j < 2; j++){
          accg[rt][j] = (f32x4){0.f, 0.f, 0.f, 0.f};
          accm[rt][j] = (f32x4){0.f, 0.f, 0.f, 0.f};
        }
      // hd part: gate only (Wg1 rows 0..127)
#pragma unroll
      for (int kt = 0; kt < 4; kt++){
        bf16x8 a[4];
#pragma unroll
        for (int rt = 0; rt < 4; rt++) a[rt] = *(const bf16x8*)&smA[rt * 16 + ln][kt * 32 + kq];
#pragma unroll
        for (int rt = 0; rt < 4; rt++)
#pragma unroll
          for (int j = 0; j < 2; j++)
            accg[rt][j] = __builtin_amdgcn_mfma_f32_16x16x32_bf16(a[rt], wg[kt][j], accg[rt][j], 0, 0, 0);
      }
      // hs|emb part: feeds gate (kt+4) AND msg1 (kt) from the same fragment
#pragma unroll
      for (int kt = 0; kt < 6; kt++){
        bf16x8 a[4];
#pragma unroll
        for (int rt = 0; rt < 4; rt++) a[rt] = *(const bf16x8*)&smA[rt * 16 + ln][128 + kt * 32 + kq];
#pragma unroll
        for (int rt = 0; rt < 4; rt++)
#pragma unroll
          for (int j = 0; j < 2; j++){
            accg[rt][j] = __builtin_amdgcn_mfma_f32_16x16x32_bf16(a[rt], wg[kt + 4][j], accg[rt][j], 0, 0, 0);
            accm[rt][j] = __builtin_amdgcn_mfma_f32_16x16x32_bf16(w1[kt][j], a[rt], accm[rt][j], 0, 0, 0);
          }
      }
      // gate epilogue: per-row partial over this wave's 32 cols -> smGP
      float p[4][4];
#pragma unroll
      for (int rt = 0; rt < 4; rt++)
#pragma unroll
        for (int r = 0; r < 4; r++)
          p[rt][r] = gelu_f(accg[rt][0][r] + bg1r[0]) * wg2r[0]
                   + gelu_f(accg[rt][1][r] + bg1r[1]) * wg2r[1];
#pragma unroll
      for (int m = 1; m < 16; m <<= 1){
#pragma unroll
        for (int rt = 0; rt < 4; rt++)
#pragma unroll
          for (int r = 0; r < 4; r++) p[rt][r] += __shfl_xor(p[rt][r], m);
      }
      if (ln == 0){
#pragma unroll
        for (int rt = 0; rt < 4; rt++)
#pragma unroll
          for (int r = 0; r < 4; r++) smGP[wave][rt * 16 + q * 4 + r] = p[rt][r];
      }
      // msg1 epilogue (transposed): lane holds row rt*16+ln, 4 consecutive cols
#pragma unroll
      for (int rt = 0; rt < 4; rt++)
#pragma unroll
        for (int j = 0; j < 2; j++){
          ushort4 u;
          u.x = f2bf(gelu_f(accm[rt][j][0] + bm1t[j].x));
          u.y = f2bf(gelu_f(accm[rt][j][1] + bm1t[j].y));
          u.z = f2bf(gelu_f(accm[rt][j][2] + bm1t[j].z));
          u.w = f2bf(gelu_f(accm[rt][j][3] + bm1t[j].w));
          *(ushort4*)&smT[rt * 16 + ln][wave * 32 + j * 16 + q * 4] = u;
        }
    }
    __syncthreads();   // syncC: smGP + smT ready

    // ---- wave-private gate table: DS ops in-order per wave -> no barrier ----
    {
      float sgp = smGP[0][lane] + smGP[1][lane] + smGP[2][lane] + smGP[3][lane] + bg2v;
      smGateW[wave][lane] = 1.f / (1.f + expf(-sgp));
    }
    __builtin_amdgcn_wave_barrier();   // keep compiler from reordering the read above the write

    // ---- msg layer 2 + gate*msg + store + scatter (untransposed: atomic merge) ----
    {
      float4 gv4[4];
#pragma unroll
      for (int rt = 0; rt < 4; rt++) gv4[rt] = *(const float4*)&smGateW[wave][rt * 16 + q * 4];
      f32x4 acc[4][2];
#pragma unroll
      for (int rt = 0; rt < 4; rt++)
#pragma unroll
        for (int j = 0; j < 2; j++) acc[rt][j] = (f32x4){0.f, 0.f, 0.f, 0.f};
#pragma unroll
      for (int kt = 0; kt < 4; kt++){
        bf16x8 a[4];
#pragma unroll
        for (int rt = 0; rt < 4; rt++) a[rt] = *(const bf16x8*)&smT[rt * 16 + ln][kt * 32 + kq];
#pragma unroll
        for (int rt = 0; rt < 4; rt++)
#pragma unroll
          for (int j = 0; j < 2; j++)
            acc[rt][j] = __builtin_amdgcn_mfma_f32_16x16x32_bf16(a[rt], w2[kt][j], acc[rt][j], 0, 0, 0);
      }
#pragma unroll
      for (int rt = 0; rt < 4; rt++)
#pragma unroll
        for (int j = 0; j < 2; j++){
          const int col = wave * 32 + j * 16 + ln;
          const float bia = bm2r[j];
#pragma unroll
          for (int r = 0; r < 4; r++){
            const int row = rt * 16 + q * 4 + r;
            const float val = gv4[rt][r] * (acc[rt][j][r] + bia);
            out_e[(size_t)(e0 + row) * 128 + col] = val;
            atomicAdd(&agg[(size_t)smDst[row] * 128 + col], val);
          }
        }
    }
  }
}

// ---------------- persistent fused node kernel: 32 nodes/tile ----------------
// v2: 768 persistent blocks (3/CU), per-wave column-split weights loaded ONCE
// into registers (was: every block re-streaming 384 KB from L2 inside the
// MFMA loops), transposed epilogues -> float4 x-loads / smO / out stores.
__global__ __launch_bounds__(256, 3) void node_kernel(
    const float* __restrict__ x, const unsigned short* __restrict__ h_bf,
    const float* __restrict__ agg, const float* __restrict__ deg,
    const unsigned short* __restrict__ Wselfp, const float* __restrict__ bself,
    const unsigned short* __restrict__ Waggp, const float* __restrict__ bagg,
    const float* __restrict__ ln2g, const float* __restrict__ ln2b,
    const unsigned short* __restrict__ Wf1p, const float* __restrict__ bf1,
    const unsigned short* __restrict__ Wf2p, const float* __restrict__ bf2,
    float* __restrict__ out, int n)
{
  __shared__ __align__(16) unsigned short smH[32][136];
  __shared__ __align__(16) unsigned short smG[32][136];
  __shared__ __align__(16) float smO[32][132];
  __shared__ __align__(16) unsigned short smU[32][264];

  const int t = threadIdx.x;
  const int wave = t >> 6, lane = t & 63;
  const int q = lane >> 4, ln = lane & 15;
  const int kq = q * 8;

  // ---- per-wave weight slices (self/agg/f2: 32 cols; f1: 64 cols) ----
  bf16x8 ws[4][2], wa[4][2], w1f[4][4], w2f[8][2];
  float4 bsat[2], bf1t[4], bf2t[2];
#pragma unroll
  for (int j = 0; j < 2; j++){
    const int col = wave * 32 + j * 16 + ln;
#pragma unroll
    for (int kt = 0; kt < 4; kt++){
      ws[kt][j] = *(const bf16x8*)(Wselfp + (((size_t)kt * 128 + col) * 4 + q) * 8);
      wa[kt][j] = *(const bf16x8*)(Waggp  + (((size_t)kt * 128 + col) * 4 + q) * 8);
    }
#pragma unroll
    for (int kt = 0; kt < 8; kt++)
      w2f[kt][j] = *(const bf16x8*)(Wf2p + (((size_t)kt * 128 + col) * 4 + q) * 8);
    const int cb = wave * 32 + j * 16 + q * 4;
    float4 b1 = *(const float4*)(bself + cb);
    float4 b2 = *(const float4*)(bagg + cb);
    bsat[j].x = b1.x + b2.x; bsat[j].y = b1.y + b2.y;
    bsat[j].z = b1.z + b2.z; bsat[j].w = b1.w + b2.w;
    bf2t[j] = *(const float4*)(bf2 + cb);
  }
#pragma unroll
  for (int j = 0; j < 4; j++){
    const int col = wave * 64 + j * 16 + ln;
#pragma unroll
    for (int kt = 0; kt < 4; kt++)
      w1f[kt][j] = *(const bf16x8*)(Wf1p + (((size_t)kt * 256 + col) * 4 + q) * 8);
    bf1t[j] = *(const float4*)(bf1 + wave * 64 + j * 16 + q * 4);
  }

  const int r8 = t >> 3, i8 = t & 7;   // staging/LN: 8 threads per node row

  for (int tile = blockIdx.x; tile < NODE_TILES; tile += gridDim.x){
    const int n0 = tile * 32;
    __syncthreads();   // prior tile's smU/smO/smH/smG consumers done

    // ---- stage h (bf16) and agg/deg (bf16) ----
    {
      int gr = n0 + r8; if (gr >= n) gr = n - 1;
      const uint4* hp = (const uint4*)(h_bf + (size_t)gr * 128 + i8 * 16);
      uint4* dp = (uint4*)&smH[r8][i8 * 16];
      dp[0] = hp[0]; dp[1] = hp[1];
      float sc = 1.f / fmaxf(deg[gr], 1.f);
      const float4* ap = (const float4*)(agg + (size_t)gr * 128 + i8 * 16);
#pragma unroll
      for (int k2 = 0; k2 < 4; k2++){
        float4 f = ap[k2];
        ushort4 u; u.x = f2bf(f.x * sc); u.y = f2bf(f.y * sc); u.z = f2bf(f.z * sc); u.w = f2bf(f.w * sc);
        *(ushort4*)&smG[r8][i8 * 16 + k2 * 4] = u;
      }
    }
    __syncthreads();

    // ---- update = x + h@Wself + agg@Wagg + biases -> smO (transposed epilogue) ----
    {
      f32x4 acc[2][2];
#pragma unroll
      for (int rt = 0; rt < 2; rt++)
#pragma unroll
        for (int j = 0; j < 2; j++) acc[rt][j] = (f32x4){0.f, 0.f, 0.f, 0.f};
#pragma unroll
      for (int kt = 0; kt < 4; kt++){
        bf16x8 a[2], g[2];
#pragma unroll
        for (int rt = 0; rt < 2; rt++){
          a[rt] = *(const bf16x8*)&smH[rt * 16 + ln][kt * 32 + kq];
          g[rt] = *(const bf16x8*)&smG[rt * 16 + ln][kt * 32 + kq];
        }
#pragma unroll
        for (int rt = 0; rt < 2; rt++)
#pragma unroll
          for (int j = 0; j < 2; j++){
            acc[rt][j] = __builtin_amdgcn_mfma_f32_16x16x32_bf16(ws[kt][j], a[rt], acc[rt][j], 0, 0, 0);
            acc[rt][j] = __builtin_amdgcn_mfma_f32_16x16x32_bf16(wa[kt][j], g[rt], acc[rt][j], 0, 0, 0);
          }
      }
#pragma unroll
      for (int rt = 0; rt < 2; rt++){
        const int row = rt * 16 + ln;
        int gr = n0 + row; if (gr >= n) gr = n - 1;
#pragma unroll
        for (int j = 0; j < 2; j++){
          const int cb = wave * 32 + j * 16 + q * 4;
          const float4 xv = *(const float4*)(x + (size_t)gr * 128 + cb);
          float4 o;
          o.x = xv.x + acc[rt][j][0] + bsat[j].x;
          o.y = xv.y + acc[rt][j][1] + bsat[j].y;
          o.z = xv.z + acc[rt][j][2] + bsat[j].z;
          o.w = xv.w + acc[rt][j][3] + bsat[j].w;
          *(float4*)&smO[row][cb] = o;
        }
      }
    }
    __syncthreads();

    // ---- LN2 over smO rows -> smH (bf16) ----
    {
      float v[16];
      float s = 0.f, s2 = 0.f;
      const float4* op = (const float4*)&smO[r8][i8 * 16];
#pragma unroll
      for (int k2 = 0; k2 < 4; k2++){
        float4 f = op[k2];
        v[k2 * 4 + 0] = f.x; v[k2 * 4 + 1] = f.y; v[k2 * 4 + 2] = f.z; v[k2 * 4 + 3] = f.w;
        s += f.x + f.y + f.z + f.w;
        s2 += f.x * f.x + f.y * f.y + f.z * f.z + f.w * f.w;
      }
#pragma unroll
      for (int m = 1; m < 8; m <<= 1){ s += __shfl_xor(s, m); s2 += __shfl_xor(s2, m); }
      float mu = s * (1.f / 128.f);
      float var = s2 * (1.f / 128.f) - mu * mu;
      float rs = rsqrtf(var + 1e-5f);
#pragma unroll
      for (int c2 = 0; c2 < 16; c2++){
        int col = i8 * 16 + c2;
        smH[r8][col] = f2bf((v[c2] - mu) * rs * ln2g[col] + ln2b[col]);
      }
    }
    __syncthreads();

    // ---- FFN up: gelu(smH @ Wf1 + b) -> smU (transposed ushort4 writes) ----
    {
      f32x4 au[2][4];
#pragma unroll
      for (int rt = 0; rt < 2; rt++)
#pragma unroll
        for (int j = 0; j < 4; j++) au[rt][j] = (f32x4){0.f, 0.f, 0.f, 0.f};
#pragma unroll
      for (int kt = 0; kt < 4; kt++){
        bf16x8 a[2];
#pragma unroll
        for (int rt = 0; rt < 2; rt++) a[rt] = *(const bf16x8*)&smH[rt * 16 + ln][kt * 32 + kq];
#pragma unroll
        for (int rt = 0; rt < 2; rt++)
#pragma unroll
          for (int j = 0; j < 4; j++)
            au[rt][j] = __builtin_amdgcn_mfma_f32_16x16x32_bf16(w1f[kt][j], a[rt], au[rt][j], 0, 0, 0);
      }
#pragma unroll
      for (int rt = 0; rt < 2; rt++){
        const int row = rt * 16 + ln;
#pragma unroll
        for (int j = 0; j < 4; j++){
          const int cb = wave * 64 + j * 16 + q * 4;
          ushort4 u;
          u.x = f2bf(gelu_f(au[rt][j][0] + bf1t[j].x));
          u.y = f2bf(gelu_f(au[rt][j][1] + bf1t[j].y));
          u.z = f2bf(gelu_f(au[rt][j][2] + bf1t[j].z));
          u.w = f2bf(gelu_f(au[rt][j][3] + bf1t[j].w));
          *(ushort4*)&smU[row][cb] = u;
        }
      }
    }
    __syncthreads();

    // ---- FFN down + residual -> out (transposed float4 stores) ----
    {
      f32x4 a2[2][2];
#pragma unroll
      for (int rt = 0; rt < 2; rt++)
#pragma unroll
        for (int j = 0; j < 2; j++) a2[rt][j] = (f32x4){0.f, 0.f, 0.f, 0.f};
#pragma unroll
      for (int kt = 0; kt < 8; kt++){
        bf16x8 a[2];
#pragma unroll
        for (int rt = 0; rt < 2; rt++) a[rt] = *(const bf16x8*)&smU[rt * 16 + ln][kt * 32 + kq];
#pragma unroll
        for (int rt = 0; rt < 2; rt++)
#pragma unroll
          for (int j = 0; j < 2; j++)
            a2[rt][j] = __builtin_amdgcn_mfma_f32_16x16x32_bf16(w2f[kt][j], a[rt], a2[rt][j], 0, 0, 0);
      }
#pragma unroll
      for (int rt = 0; rt < 2; rt++){
        const int row = rt * 16 + ln;
        const int gr = n0 + row;
        if (gr < n){
#pragma unroll
          for (int j = 0; j < 2; j++){
            const int cb = wave * 32 + j * 16 + q * 4;
            const float4 ov = *(const float4*)&smO[row][cb];
            float4 o;
            o.x = ov.x + a2[rt][j][0] + bf2t[j].x;
            o.y = ov.y + a2[rt][j][1] + bf2t[j].y;
            o.z = ov.z + a2[rt][j][2] + bf2t[j].z;
            o.w = ov.w + a2[rt][j][3] + bf2t[j].w;
            *(float4*)(out + (size_t)gr * 128 + cb) = o;
          }
        }
      }
    }
  }
}

extern "C" void kernel_launch(void* const* d_in, const int* in_sizes, int n_in,
                              void* d_out, int out_size, void* d_ws, size_t ws_size,
                              hipStream_t stream){
  const float* x     = (const float*)d_in[0];
  const int*   esrc  = (const int*)d_in[1];
  const int*   edst  = (const int*)d_in[2];
  const float* eemb  = (const float*)d_in[3];
  const float* ln1g  = (const float*)d_in[4];
  const float* ln1b  = (const float*)d_in[5];
  const float* Wself = (const float*)d_in[6];
  const float* bself = (const float*)d_in[7];
  const float* Wm1   = (const float*)d_in[8];
  const float* bm1   = (const float*)d_in[9];
  const float* Wm2   = (const float*)d_in[10];
  const float* bm2   = (const float*)d_in[11];
  const float* Wg1   = (const float*)d_in[12];
  const float* bg1   = (const float*)d_in[13];
  const float* wg2   = (const float*)d_in[14];
  const float* bg2   = (const float*)d_in[15];
  const float* Wagg  = (const float*)d_in[16];
  const float* bagg  = (const float*)d_in[17];
  const float* ln2g  = (const float*)d_in[18];
  const float* ln2b  = (const float*)d_in[19];
  const float* Wf1   = (const float*)d_in[20];
  const float* bf1   = (const float*)d_in[21];
  const float* Wf2   = (const float*)d_in[22];
  const float* bf2   = (const float*)d_in[23];

  char* ws = (char*)d_ws;
  float* agg = (float*)(ws + 0);                              // 25,600,000 B
  float* deg = (float*)(ws + 25600000);                       //    200,000 B
  unsigned short* h_bf = (unsigned short*)(ws + 25800000);    // 12,800,000 B
  unsigned short* Wselfp = (unsigned short*)(ws + 38600000);
  unsigned short* Wm1p  = Wselfp + 16384;
  unsigned short* Wm2p  = Wm1p + 24576;
  unsigned short* Wg1p  = Wm2p + 16384;
  unsigned short* Waggp = Wg1p + 40960;
  unsigned short* Wf1p  = Waggp + 16384;
  unsigned short* Wf2p  = Wf1p + 32768;

  hipMemsetAsync(agg, 0, 25600000 + 200000, stream);

  pack_kernel<<<64, 256, 0, stream>>>(Wself, Wselfp, 128, 128);
  pack_kernel<<<96, 256, 0, stream>>>(Wm1, Wm1p, 192, 128);
  pack_kernel<<<64, 256, 0, stream>>>(Wm2, Wm2p, 128, 128);
  pack_kernel<<<160, 256, 0, stream>>>(Wg1, Wg1p, 320, 128);
  pack_kernel<<<64, 256, 0, stream>>>(Wagg, Waggp, 128, 128);
  pack_kernel<<<128, 256, 0, stream>>>(Wf1, Wf1p, 128, 256);
  pack_kernel<<<128, 256, 0, stream>>>(Wf2, Wf2p, 256, 128);

  ln1_kernel<<<12500, 256, 0, stream>>>(x, ln1g, ln1b, h_bf, N_NODES);

  float* out_nodes = (float*)d_out;
  float* out_edges = out_nodes + (size_t)N_NODES * 128;

  edge_kernel<<<512, 256, 0, stream>>>(h_bf, esrc, edst, eemb,
      Wm1p, bm1, Wm2p, bm2, Wg1p, bg1, wg2, bg2, out_edges, agg, deg);

  node_kernel<<<768, 256, 0, stream>>>(x, h_bf, agg, deg,
      Wselfp, bself, Waggp, bagg, ln2g, ln2b, Wf1p, bf1, Wf2p, bf2, out_nodes, N_NODES);
}